// Round 7
// baseline (214.366 us; speedup 1.0000x reference)
//
#include <hip/hip_runtime.h>
#include <hip/hip_fp16.h>

// ---------------------------------------------------------------------------
// SoftDecisionTreeEnsemble: N_TREES=15, DEPTH=3, INPUT_DIM=128, N_CLASSES=10
// R9: TLP attack on the good chassis. All prior structures sat at 2 waves/SIMD
// (112 resident weight VGPRs) and per-CU x-BW stuck at ~2.6 B/cyc vs 10
// streaming ceiling; nothing else is saturated (R6/R7 counters). Now:
//   - z-GEMM weights live in a 28.7KB LDS copy (cooperative swizzled copy at
//     block start + 1 barrier). Phase A reads them per-nt, 2-deep rotate,
//     unroll-1 pair loop (stops LICM re-hoisting 112 VGPRs - R3 lesson).
//     Swizzle lds[row][(c+row)&15] -> bank-optimal ds_read_b128, zero
//     in-loop VALU (precomputed addr_s; +nt*4096 per iter).
//   - 512-thread blocks, __launch_bounds__(512,4): VGPR<=128, 2 blocks/CU,
//     16 waves/CU = 4 waves/SIMD (2x TLP/MLP).
//   - x direct-to-register (R8 path), single xa buffer, full one-tile
//     prefetch distance (reload xa right after cvt consumes it).
//   - grid 512 x 4 tiles of 128 rows: all blocks resident, no tail.
// ---------------------------------------------------------------------------

typedef float    f32x4 __attribute__((ext_vector_type(4)));
typedef _Float16 half8 __attribute__((ext_vector_type(8)));

#define TREES      15
#define IDIM       128
#define NCLS       10
#define NINT       7
#define NLVS       8
#define PER_TREE   (NINT*IDIM + NINT + NLVS*NCLS)   // 983
#define NODES      (TREES*NINT)                     // 105
#define NPAD       112                              // 7 n-tiles of 16
#define KPAD       128                              // leaf K padded
#define RSTR       272                              // scratch row stride bytes (136 halves)
#define WSTR       4352                             // per-wave scratch: 16 rows * 272B
#define NBLK       512                              // 2 blocks/CU (512 thr)

// ---------------------------------------------------------------------------
// prep: wq[112][128] f16 (row g=7t+n, zero-padded), bq[112] f32 (zero-padded),
//       wbT[16][128] f16: wbT[c][8t+l] = softmax(leaf_logits[t][l])[c]*tw[t].
// Zero padding is load-bearing: padded nodes give z=0 -> sigmoid 0.5 ->
// garbage-free; padded leaf cols/classes contribute 0.
// ---------------------------------------------------------------------------
__global__ __launch_bounds__(256) void prep_kernel(const float* __restrict__ p,
                                                   _Float16* __restrict__ wq,
                                                   float* __restrict__ bq,
                                                   _Float16* __restrict__ wbT) {
    const int gid  = blockIdx.x * 256 + threadIdx.x;
    const int nthr = gridDim.x * 256;

    for (int i = gid; i < NPAD * IDIM; i += nthr) {
        int g = i >> 7, k = i & 127;
        float v = 0.f;
        if (g < NODES) {
            int t = g / NINT, n = g % NINT;
            v = p[t * PER_TREE + n * IDIM + k];
        }
        wq[i] = (_Float16)v;
    }
    for (int i = gid; i < NPAD; i += nthr) {
        float v = 0.f;
        if (i < NODES) {
            int t = i / NINT, n = i % NINT;
            v = p[t * PER_TREE + NINT * IDIM + n];
        }
        bq[i] = v;
    }
    const float* tl = p + TREES * PER_TREE;
    for (int i = gid; i < 16 * KPAD; i += nthr) {
        int c = i >> 7, k = i & 127;
        float v = 0.f;
        if (c < NCLS && k < TREES * NLVS) {
            int t = k >> 3, l = k & 7;
            const float* ll = p + t * PER_TREE + NINT * IDIM + NINT + l * NCLS;
            float mx = ll[0];
            #pragma unroll
            for (int j = 1; j < NCLS; ++j) mx = fmaxf(mx, ll[j]);
            float se = 0.f;
            #pragma unroll
            for (int j = 0; j < NCLS; ++j) se += __expf(ll[j] - mx);
            float lsm = __expf(ll[c] - mx) / se;

            float m2 = tl[0];
            #pragma unroll
            for (int j = 1; j < TREES; ++j) m2 = fmaxf(m2, tl[j]);
            float s2 = 0.f;
            #pragma unroll
            for (int j = 0; j < TREES; ++j) s2 += __expf(tl[j] - m2);
            float tw = __expf(tl[t] - m2) / s2;
            v = lsm * tw;
        }
        wbT[i] = (_Float16)v;
    }
}

// load one tile's A-fragment data for this lane: x[row][32s+8lq .. +7]
__device__ __forceinline__ void load_xa(const float* __restrict__ xr,
                                        f32x4 (&xa)[8]) {
    #pragma unroll
    for (int s = 0; s < 4; ++s) {
        xa[2 * s]     = *(const f32x4*)(xr + 32 * s);
        xa[2 * s + 1] = *(const f32x4*)(xr + 32 * s + 4);
    }
}

// ---------------------------------------------------------------------------
__global__ __launch_bounds__(512, 4) void tree_main(const float* __restrict__ x,
                                                    const _Float16* __restrict__ wq,
                                                    const float* __restrict__ bq,
                                                    const _Float16* __restrict__ wbT,
                                                    float* __restrict__ out,
                                                    int tpb) {
    __shared__ __align__(16) char lwq[NPAD * 256];   // 28672: swizzled weights
    __shared__ __align__(16) char sls[8 * WSTR];     // 34816: per-wave scratch

    const int tid  = threadIdx.x;
    const int lane = tid & 63;
    const int w    = tid >> 6;        // wave id 0..7: owns tile rows 16w..16w+15
    const int lm   = lane & 15;
    const int lq   = lane >> 4;
    const int rg   = lane >> 2;       // Phase B row (0..15)
    const int g    = lane & 3;        // Phase B tree group

    char* sbuf = &sls[w * WSTR];      // per-wave scratch: 16 rows x 272B
    const long tile0 = (long)blockIdx.x * tpb;       // 128-row tiles

    // this lane's x pointer for tile 0; advances 128*IDIM floats per tile
    const float* xlane = x + (tile0 * 128 + 16 * w + lm) * IDIM + 8 * lq;

    // prefetch tile 0 A-data into registers (overlaps weight copy below)
    f32x4 xa[8];
    load_xa(xlane, xa);

    // ---- cooperative swizzled copy of wq into LDS --------------------------
    // lwq[row][(c+row)&15] = wq[row][c]  (c = 16B column 0..15). The rotation
    // makes the Phase-A fragment ds_read_b128 bank-optimal (8 lanes/quad,
    // 1 per phase). Consecutive tids copy consecutive c (coalesced 256B).
    for (int k = tid; k < NPAD * 16; k += 512) {
        int row = k >> 4, c = k & 15;
        half8 v = *reinterpret_cast<const half8*>(wq + row * 128 + c * 8);
        *(half8*)(lwq + row * 256 + (((c + row) & 15) << 4)) = v;
    }

    // resident small weights: biases (7) + Phase C class frags (16 VGPR).
    float bb[7];
    #pragma unroll
    for (int nt = 0; nt < 7; ++nt) bb[nt] = bq[16 * nt + lm];
    half8 wbf[4];
    #pragma unroll
    for (int s = 0; s < 4; ++s)
        wbf[s] = *reinterpret_cast<const half8*>(wbT + lm * KPAD + 32 * s + 8 * lq);

    // per-lane swizzled fragment addresses: row = 16nt+lm -> rotation
    // (c+row)&15 = (4s+lq+lm)&15 (16nt == 0 mod 16). addr = addr_s + nt*4096.
    int addr_s[4];
    #pragma unroll
    for (int s = 0; s < 4; ++s)
        addr_s[s] = lm * 256 + (((4 * s + lq + lm) & 15) << 4);

    __syncthreads();                  // lwq ready for all waves

    for (int i = 0; i < tpb; ++i) {
        const long grow = (tile0 + i) * 128;

        // convert A to f16 fragments (waits on xa loads, issued 1 tile ago)
        half8 af[4];
        #pragma unroll
        for (int s = 0; s < 4; ++s) {
            half8 a;
            #pragma unroll
            for (int j = 0; j < 4; ++j) {
                a[j]     = (_Float16)xa[2 * s][j];
                a[j + 4] = (_Float16)xa[2 * s + 1][j];
            }
            af[s] = a;
        }

        // xa now dead: immediately reissue next tile's loads into it
        // (full one-tile prefetch distance, single buffer).
        if (i + 1 < tpb)
            load_xa(xlane + (long)(i + 1) * 128 * IDIM, xa);

        // ---- Phase A: z-GEMM + sigmoid -> packed cols 8t+n -----------------
        // weights from LDS, 2-deep rotate, pair loop at unroll 1 so the
        // compiler cannot hoist all 7 nt fragments into registers.
        auto pa_compute = [&](int nt, half8 (&bf)[4]) {
            f32x4 acc = {bb[nt], bb[nt], bb[nt], bb[nt]};
            #pragma unroll
            for (int s = 0; s < 4; ++s)
                acc = __builtin_amdgcn_mfma_f32_16x16x32_f16(af[s], bf[s], acc, 0, 0, 0);
            int node = 16 * nt + lm;
            int col  = node + ((node * 9363) >> 16);   // node + node/7 = 8t+n
            #pragma unroll
            for (int r = 0; r < 4; ++r) {
                float z  = acc[r];                     // C/D: row=4lq+r, col=lm
                float sg = __builtin_amdgcn_rcpf(1.0f + __expf(-z));
                *(_Float16*)(sbuf + (4 * lq + r) * RSTR + col * 2) = (_Float16)sg;
            }
        };
        half8 bfA[4], bfB[4];
        #pragma unroll
        for (int s = 0; s < 4; ++s)
            bfA[s] = *(const half8*)(lwq + addr_s[s]);           // nt=0
        #pragma unroll 1
        for (int ntp = 0; ntp < 3; ++ntp) {
            const int base = ntp * 8192;                          // 2 nt * 4096
            #pragma unroll
            for (int s = 0; s < 4; ++s)
                bfB[s] = *(const half8*)(lwq + addr_s[s] + base + 4096);
            pa_compute(2 * ntp, bfA);
            #pragma unroll
            for (int s = 0; s < 4; ++s)
                bfA[s] = *(const half8*)(lwq + addr_s[s] + base + 8192);
            pa_compute(2 * ntp + 1, bfB);
        }
        pa_compute(6, bfA);

        // ---- Phase B: leaf probabilities (wave-lockstep, reads before writes)
        // b128 gather: tree t=4g+tt at halves [8t..8t+7] = byte 16t,
        // 16B-aligned since RSTR=272=17*16.
        {
            const char* rowp = sbuf + rg * RSTR;
            half8 hv[4];
            #pragma unroll
            for (int tt = 0; tt < 4; ++tt)
                hv[tt] = *(const half8*)(rowp + 64 * g + 16 * tt);
            half8 lv[4];
            #pragma unroll
            for (int tt = 0; tt < 4; ++tt) {
                float s0 = (float)hv[tt][0], s1 = (float)hv[tt][1], s2v = (float)hv[tt][2];
                float s3 = (float)hv[tt][3], s4 = (float)hv[tt][4], s5 = (float)hv[tt][5];
                float s6 = (float)hv[tt][6];
                float u1 = 1.f - s0, u2 = s0;
                float q1 = u1 * s1, q0 = u1 - q1;
                float q3 = u2 * s2v, q2 = u2 - q3;
                float L1 = q0 * s3, L0 = q0 - L1;
                float L3 = q1 * s4, L2 = q1 - L3;
                float L5 = q2 * s5, L4 = q2 - L5;
                float L7 = q3 * s6, L6 = q3 - L7;
                float m = (4 * g + tt < TREES) ? 1.f : 0.f;   // zero tree-15 slot
                half8 lv8;
                lv8[0] = (_Float16)(L0 * m); lv8[1] = (_Float16)(L1 * m);
                lv8[2] = (_Float16)(L2 * m); lv8[3] = (_Float16)(L3 * m);
                lv8[4] = (_Float16)(L4 * m); lv8[5] = (_Float16)(L5 * m);
                lv8[6] = (_Float16)(L6 * m); lv8[7] = (_Float16)(L7 * m);
                lv[tt] = lv8;
            }
            #pragma unroll
            for (int tt = 0; tt < 4; ++tt)
                *(half8*)(sbuf + rg * RSTR + 64 * g + 16 * tt) = lv[tt];
        }

        // ---- Phase C: leaf x wbT MFMA -> out ----
        {
            half8 af2[4];
            #pragma unroll
            for (int s = 0; s < 4; ++s)
                af2[s] = *(const half8*)(sbuf + lm * RSTR + 64 * s + 16 * lq);
            f32x4 a2 = {0.f, 0.f, 0.f, 0.f};
            #pragma unroll
            for (int s = 0; s < 4; ++s)
                a2 = __builtin_amdgcn_mfma_f32_16x16x32_f16(af2[s], wbf[s], a2, 0, 0, 0);
            if (lm < NCLS) {
                #pragma unroll
                for (int r = 0; r < 4; ++r)
                    out[(grow + 16 * w + 4 * lq + r) * NCLS + lm] = a2[r];
            }
        }
    }
}

// ---------------------------------------------------------------------------
extern "C" void kernel_launch(void* const* d_in, const int* in_sizes, int n_in,
                              void* d_out, int out_size, void* d_ws, size_t ws_size,
                              hipStream_t stream) {
    const float* x      = (const float*)d_in[0];
    const float* params = (const float*)d_in[1];
    float* out = (float*)d_out;

    _Float16* wq  = (_Float16*)d_ws;                             // 28672 B
    float*    bq  = (float*)((char*)d_ws + NPAD * IDIM * 2);     // 448 B
    _Float16* wbT = (_Float16*)((char*)bq + NPAD * 4);           // 4096 B

    const int batch = in_sizes[0] / IDIM;      // 262144
    const int tiles = batch / 128;             // 2048 (128-row tiles)
    const int tpb   = tiles / NBLK;            // 4

    prep_kernel<<<8, 256, 0, stream>>>(params, wq, bq, wbT);
    tree_main<<<NBLK, 512, 0, stream>>>(x, wq, bq, wbT, out, tpb);
}